// Round 12
// baseline (49.927 us; speedup 1.0000x reference)
//
#include <hip/hip_runtime.h>

// RefCondMul: x[B=4][64][L=8192] f32, inds[B][L] int32, w[1000][64][64] f32,
// bias[1000][1][64] f32 -> out[B][64][L] f32.
// out[b][o][l] = sum_m x[b][m][l] * w[inds[b][l]][m][o] + bias[inds[b][l]][0][o]
//
// Class-binning, 4-stage pipeline (stage-minimal: atomic binning requires
// counter init across a boundary; R7 showed serial scatter = 35us, R10 showed
// grid.sync ~100us/sync). R11 = 37.7us. R12 micro-opts: (1) k_main all-b128
// LDS reads (-32% LDS issue), (2) tin/tout at 1024 blocks / 32-l tiles
// (2x TLP on latency-tail-bound transposes). Tile logic = R10's validated
// P4/P6 phases.

#define M_DIM 64
#define N_OUTD 64
#define L_DIM 8192
#define B_DIM 4
#define NCLS 1000
#define NSAMP (B_DIM * L_DIM)

typedef float float4v __attribute__((ext_vector_type(4)));
typedef int   int4v   __attribute__((ext_vector_type(4)));

// ---- workspace layout (bytes) ----
#define XG_OFF   0ull            // xg[NSAMP][64] f32, binned order : 8 MB
#define OTB_OFF  8388608ull      // otb[NSAMP][64] f32, binned      : 8 MB
#define RANK_OFF 16777216ull     // rank[NSAMP] int (n -> pos)      : 128 KB
#define OFFS_OFF 16908288ull     // offs[1001] int
#define CUR_OFF  16912384ull     // cur[1000] int (scatter cursors)
#define WS_NEED  16916384ull

// ============ kernel 1: histogram + scan (1 block, 1024 threads) ============
__global__ __launch_bounds__(1024) void k_binprep(
    const int* __restrict__ inds, int* __restrict__ offs, int* __restrict__ cur) {
  __shared__ int h[1024];
  __shared__ int s[1024];
  const int tid = threadIdx.x;
  h[tid] = 0;
  __syncthreads();
  const int4v* ip = (const int4v*)inds;   // NSAMP/4 = 8192 int4s
#pragma unroll
  for (int r = 0; r < NSAMP / 4 / 1024; ++r) {   // 8 int4 per thread
    int4v v = ip[r * 1024 + tid];
    atomicAdd(&h[v.x], 1); atomicAdd(&h[v.y], 1);
    atomicAdd(&h[v.z], 1); atomicAdd(&h[v.w], 1);
  }
  __syncthreads();
  const int v = h[tid];
  s[tid] = v;
  __syncthreads();
  for (int off = 1; off < 1024; off <<= 1) {     // Hillis-Steele inclusive
    int t = (tid >= off) ? s[tid - off] : 0;
    __syncthreads();
    s[tid] += t;
    __syncthreads();
  }
  if (tid < NCLS) {
    const int excl = s[tid] - v;
    offs[tid] = excl;
    cur[tid]  = excl;
  }
  if (tid == NCLS - 1) offs[NCLS] = s[tid];      // total = NSAMP
}

// ============ kernel 2: transpose-in + parallel scatter (1024 blocks) =======
// Each block owns 32 consecutive l of one b: claims binned positions via
// device atomics, writes x columns straight to xg[pos][0..63] (256B/sample)
// and rank[n]=pos. (= R10's validated P4 phase.)
__global__ __launch_bounds__(256) void k_tin_scatter(
    const float* __restrict__ x, const int* __restrict__ inds,
    int* __restrict__ cur, float* __restrict__ xg, int* __restrict__ rank) {
  __shared__ float tile[32][68];  // [l][m], padded
  __shared__ int posv[32];
  const int tid = threadIdx.x;
  const int b  = blockIdx.x >> 8;
  const int l0 = (blockIdx.x & 255) << 5;

  if (tid < 32) {
    const int n = b * L_DIM + l0 + tid;
    const int pos = atomicAdd(&cur[inds[n]], 1);
    posv[tid] = pos;
    rank[n] = pos;
  }

  const float* xb = x + ((size_t)b * M_DIM) * L_DIM + l0;
#pragma unroll
  for (int p = 0; p < 2; ++p) {                  // 512 float4 loads / block
    const int idx = p * 256 + tid;
    const int m = idx >> 3;                      // 0..63
    const int f = (idx & 7) * 4;                 // 0..28
    float4v v = *(const float4v*)(xb + (size_t)m * L_DIM + f);   // 128B segs
    tile[f + 0][m] = v[0]; tile[f + 1][m] = v[1];
    tile[f + 2][m] = v[2]; tile[f + 3][m] = v[3];
  }
  __syncthreads();
#pragma unroll
  for (int p = 0; p < 2; ++p) {
    const int idx = p * 256 + tid;
    const int li = idx >> 4;                     // 0..31
    const int q  = (idx & 15) * 4;               // 0..60
    float4v v = *(const float4v*)(&tile[li][q]);
    *(float4v*)(xg + (size_t)posv[li] * M_DIM + q) = v;  // 256B/sample
  }
}

// ============ kernel 3: binned matvec, 4 samples per 16-lane group ==========
// grid = 1000 (one block per class). 64 samples per block-iteration (16
// groups x 4 samples). All LDS reads are b128: per 4-m chunk, 4 w-row reads
// shared by 4 samples + 4 per-sample x reads (was 4 b128 + 16 b32 in R11).
__global__ __launch_bounds__(256) void k_main(
    const float* __restrict__ xg, const int* __restrict__ offs,
    const float* __restrict__ w, const float* __restrict__ bias,
    float* __restrict__ otb) {
  __shared__ float wl[4096];        // w[c]: 16 KB
  __shared__ float xs[64][68];      // 64 samples' x, padded rows (17.4 KB)

  const int tid = threadIdx.x;
  const int c   = blockIdx.x;
  const int start = offs[c];
  const int count = offs[c + 1] - start;

  // stage w[c] into LDS (coalesced: wave reads 1KB contiguous per inst)
  const float* wp = w + (size_t)c * (M_DIM * N_OUTD);
#pragma unroll
  for (int p = 0; p < 4; ++p) {
    const int idx = (p * 256 + tid) * 4;
    *(float4v*)(&wl[idx]) = *(const float4v*)(wp + idx);
  }

  const int wid  = tid >> 6;
  const int lane = tid & 63;
  const int G    = wid * 4 + (lane >> 4);   // group 0..15
  const int oi   = (lane & 15) * 4;         // output base (float4)
  const int jb   = G * 4;                   // this group's first sample slot

  const float4v bv = *(const float4v*)(bias + (size_t)c * N_OUTD + oi);

  for (int s0 = 0; s0 < count; s0 += 64) {
    __syncthreads();  // xs reuse guard (iter>0); wl ready (iter 0)
    // stage up to 64 samples (contiguous 16KB block of xg)
#pragma unroll
    for (int p = 0; p < 4; ++p) {
      const int idx = p * 256 + tid;
      const int row = idx >> 4;             // 0..63
      const int c4  = (idx & 15) * 4;
      if (s0 + row < count)
        *(float4v*)(&xs[row][c4]) = *(const float4v*)(xg + (size_t)(start + s0 + row) * M_DIM + c4);
    }
    __syncthreads();

    if (s0 + jb < count) {
      float4v a0 = bv, a1 = bv, a2 = bv, a3 = bv;
#pragma unroll
      for (int m0 = 0; m0 < M_DIM; m0 += 4) {
        const float4v x0 = *(const float4v*)(&xs[jb + 0][m0]);   // b128
        const float4v x1 = *(const float4v*)(&xs[jb + 1][m0]);   // (rows beyond
        const float4v x2 = *(const float4v*)(&xs[jb + 2][m0]);   //  count read
        const float4v x3 = *(const float4v*)(&xs[jb + 3][m0]);   //  garbage; stores guarded)
#pragma unroll
        for (int mm = 0; mm < 4; ++mm) {
          const float4v wv = *(const float4v*)(&wl[(m0 + mm) * N_OUTD + oi]);  // b128, shared by 4 samples
          a0 += x0[mm] * wv;
          a1 += x1[mm] * wv;
          a2 += x2[mm] * wv;
          a3 += x3[mm] * wv;
        }
      }
      float* ob = otb + (size_t)(start + s0 + jb) * N_OUTD + oi;
      *(float4v*)(ob) = a0;                                      // jb+0 < count
      if (s0 + jb + 1 < count) *(float4v*)(ob + 1 * N_OUTD) = a1;
      if (s0 + jb + 2 < count) *(float4v*)(ob + 2 * N_OUTD) = a2;
      if (s0 + jb + 3 < count) *(float4v*)(ob + 3 * N_OUTD) = a3;
    }
  }
}

// ============ kernel 4: gather + transpose-out (1024 blocks) ================
// out[b][o][l] = otb[rank[b*L+l]][o]; 32-l tiles. (= R10's validated P6.)
__global__ __launch_bounds__(256) void k_tout(
    const float* __restrict__ otb, const int* __restrict__ rank,
    float* __restrict__ out) {
  __shared__ float t2[32][68];    // [l][o], padded
  __shared__ int rk[32];
  const int tid = threadIdx.x;
  const int b  = blockIdx.x >> 8;
  const int l0 = (blockIdx.x & 255) << 5;

  if (tid < 32) rk[tid] = rank[b * L_DIM + l0 + tid];
  __syncthreads();

#pragma unroll
  for (int p = 0; p < 2; ++p) {
    const int idx = p * 256 + tid;
    const int li = idx >> 4;                     // 0..31
    const int q  = (idx & 15) * 4;               // 0..60
    float4v v = *(const float4v*)(otb + (size_t)rk[li] * N_OUTD + q);  // 256B/row
    *(float4v*)(&t2[li][q]) = v;
  }
  __syncthreads();
  float* ob = out + ((size_t)b * N_OUTD) * L_DIM + l0;
#pragma unroll
  for (int p = 0; p < 2; ++p) {
    const int idx = p * 256 + tid;
    const int o = idx >> 3;                      // 0..63
    const int f = (idx & 7) * 4;                 // 0..28
    float4v v = {t2[f + 0][o], t2[f + 1][o], t2[f + 2][o], t2[f + 3][o]};
    *(float4v*)(ob + (size_t)o * L_DIM + f) = v; // 128B segments
  }
}

// ============ fallback (R4 kernel) if ws too small ==========================
#define TL 16
__global__ __launch_bounds__(256) void condmul_fallback(
    const float* __restrict__ x, const int* __restrict__ inds,
    const float* __restrict__ w, const float* __restrict__ bias,
    float* __restrict__ out) {
  __shared__ float xs[M_DIM][TL];
  __shared__ float os[TL][N_OUTD + 4];
  const int tid  = threadIdx.x;
  const int wid  = tid >> 6;
  const int lane = tid & 63;
  const int g    = lane >> 4;
  const int oi   = (lane & 15) * 4;
  const int n0   = blockIdx.x * TL;
  const int b    = n0 / L_DIM;
  const int l0   = n0 % L_DIM;
  {
    const int li = tid & (TL - 1);
    const int m0 = tid >> 4;
    const float* xb = x + ((size_t)b * M_DIM) * L_DIM + l0;
#pragma unroll
    for (int p = 0; p < 4; ++p) {
      const int m = p * 16 + m0;
      xs[m][li] = xb[(size_t)m * L_DIM + li];
    }
  }
  __syncthreads();
  const int li = wid * 4 + g;
  const int c  = inds[n0 + li];
  const float* wp = w + ((size_t)c * M_DIM) * N_OUTD + oi;
  float4v acc = {0.f, 0.f, 0.f, 0.f};
#pragma unroll 8
  for (int m = 0; m < M_DIM; ++m) {
    const float  xv = xs[m][li];
    const float4v wv = *(const float4v*)(wp + (size_t)m * N_OUTD);
    acc += xv * wv;
  }
  acc += *(const float4v*)(bias + (size_t)c * N_OUTD + oi);
  *(float4v*)(&os[li][oi]) = acc;
  __syncthreads();
  {
    const int lo = tid & (TL - 1);
    const int o0 = tid >> 4;
    float* ob = out + ((size_t)b * N_OUTD) * L_DIM + l0;
#pragma unroll
    for (int p = 0; p < 4; ++p) {
      const int o = p * 16 + o0;
      ob[(size_t)o * L_DIM + lo] = os[lo][o];
    }
  }
}

extern "C" void kernel_launch(void* const* d_in, const int* in_sizes, int n_in,
                              void* d_out, int out_size, void* d_ws, size_t ws_size,
                              hipStream_t stream) {
  const float* x    = (const float*)d_in[0];
  const int*   inds = (const int*)d_in[1];
  const float* w    = (const float*)d_in[2];
  const float* bias = (const float*)d_in[3];
  float*       out  = (float*)d_out;

  if (ws_size < WS_NEED) {
    condmul_fallback<<<NSAMP / TL, 256, 0, stream>>>(x, inds, w, bias, out);
    return;
  }

  char* ws = (char*)d_ws;
  float* xg   = (float*)(ws + XG_OFF);
  float* otb  = (float*)(ws + OTB_OFF);
  int*   rank = (int*)(ws + RANK_OFF);
  int*   offs = (int*)(ws + OFFS_OFF);
  int*   cur  = (int*)(ws + CUR_OFF);

  k_binprep<<<1, 1024, 0, stream>>>(inds, offs, cur);
  k_tin_scatter<<<1024, 256, 0, stream>>>(x, inds, cur, xg, rank);
  k_main<<<NCLS, 256, 0, stream>>>(xg, offs, w, bias, otb);
  k_tout<<<1024, 256, 0, stream>>>(otb, rank, out);
}

// Round 13
// 37.295 us; speedup vs baseline: 1.3387x; 1.3387x over previous
//
#include <hip/hip_runtime.h>

// RefCondMul: x[B=4][64][L=8192] f32, inds[B][L] int32, w[1000][64][64] f32,
// bias[1000][1][64] f32 -> out[B][64][L] f32.
// out[b][o][l] = sum_m x[b][m][l] * w[inds[b][l]][m][o] + bias[inds[b][l]][0][o]
//
// Class-binning, 4-stage pipeline (stage-minimal for atomic binning; R10:
// grid.sync ~100us/sync; R7: serial scatter 41us). R11 = 37.7us best.
// R12 (3-change bundle) = 49.9us REGRESSION -> fully reverted; lesson:
// one variable per round. R13 single change: binprep's 1000-entry scan
// Hillis-Steele (20 block barriers on 16 waves) -> wave-shuffle scan
// (2 barriers, 10 shfl rounds).

#define M_DIM 64
#define N_OUTD 64
#define L_DIM 8192
#define B_DIM 4
#define NCLS 1000
#define NSAMP (B_DIM * L_DIM)

typedef float float4v __attribute__((ext_vector_type(4)));
typedef int   int4v   __attribute__((ext_vector_type(4)));

// ---- workspace layout (bytes) ----
#define XG_OFF   0ull            // xg[NSAMP][64] f32, binned order : 8 MB
#define OTB_OFF  8388608ull      // otb[NSAMP][64] f32, binned      : 8 MB
#define RANK_OFF 16777216ull     // rank[NSAMP] int (n -> pos)      : 128 KB
#define OFFS_OFF 16908288ull     // offs[1001] int
#define CUR_OFF  16912384ull     // cur[1000] int (scatter cursors)
#define WS_NEED  16916384ull

// ============ kernel 1: histogram + wave-shuffle scan (1 block, 1024 thr) ===
__global__ __launch_bounds__(1024) void k_binprep(
    const int* __restrict__ inds, int* __restrict__ offs, int* __restrict__ cur) {
  __shared__ int h[1024];
  __shared__ int wsum[16];
  const int tid = threadIdx.x;
  h[tid] = 0;
  __syncthreads();
  const int4v* ip = (const int4v*)inds;   // NSAMP/4 = 8192 int4s
#pragma unroll
  for (int r = 0; r < NSAMP / 4 / 1024; ++r) {   // 8 int4 per thread
    int4v v = ip[r * 1024 + tid];
    atomicAdd(&h[v.x], 1); atomicAdd(&h[v.y], 1);
    atomicAdd(&h[v.z], 1); atomicAdd(&h[v.w], 1);
  }
  __syncthreads();

  const int v = h[tid];
  const int lane = tid & 63;
  const int wv   = tid >> 6;              // 16 waves
  // per-wave inclusive scan (no barriers)
  int val = v;
#pragma unroll
  for (int d = 1; d < 64; d <<= 1) {
    int t = __shfl_up(val, d, 64);
    if (lane >= d) val += t;
  }
  if (lane == 63) wsum[wv] = val;
  __syncthreads();
  // wave 0 scans the 16 wave totals
  if (wv == 0) {
    int wval = (lane < 16) ? wsum[lane] : 0;
#pragma unroll
    for (int d = 1; d < 16; d <<= 1) {
      int t = __shfl_up(wval, d, 64);
      if (lane >= d) wval += t;
    }
    if (lane < 16) wsum[lane] = wval;
  }
  __syncthreads();
  const int incl = val + (wv > 0 ? wsum[wv - 1] : 0);
  if (tid < NCLS) {
    const int excl = incl - v;
    offs[tid] = excl;
    cur[tid]  = excl;
  }
  if (tid == 1023) offs[NCLS] = incl;     // bins 1000..1023 empty -> = NSAMP
}

// ============ kernel 2: transpose-in + parallel scatter (512 blocks) ========
// Each block owns 64 consecutive l of one b. Claims binned positions via
// device atomics, writes x columns straight to xg[pos][0..63] (256B/sample)
// and rank[n]=pos.
__global__ __launch_bounds__(256) void k_tin_scatter(
    const float* __restrict__ x, const int* __restrict__ inds,
    int* __restrict__ cur, float* __restrict__ xg, int* __restrict__ rank) {
  __shared__ float tile[64][68];  // [l][m], padded
  __shared__ int posv[64];
  const int tid = threadIdx.x;
  const int b  = blockIdx.x >> 7;
  const int l0 = (blockIdx.x & 127) << 6;

  if (tid < 64) {
    const int n = b * L_DIM + l0 + tid;
    const int pos = atomicAdd(&cur[inds[n]], 1);
    posv[tid] = pos;
    rank[n] = pos;
  }

  const float* xb = x + ((size_t)b * M_DIM) * L_DIM + l0;
  const int r  = tid >> 4;         // 0..15
  const int c4 = (tid & 15) * 4;   // 0..60
#pragma unroll
  for (int p = 0; p < 4; ++p) {
    const int m = r + 16 * p;
    float4v v = *(const float4v*)(xb + (size_t)m * L_DIM + c4);
#pragma unroll
    for (int q = 0; q < 4; ++q) tile[c4 + q][m] = v[q];
  }
  __syncthreads();
#pragma unroll
  for (int p = 0; p < 4; ++p) {
    const int li = r + 16 * p;
    float4v v = *(const float4v*)(&tile[li][c4]);
    *(float4v*)(xg + (size_t)posv[li] * M_DIM + c4) = v;  // 256B/sample
  }
}

// ============ kernel 3: binned matvec, 4 samples per 16-lane group ==========
// grid = 1000 (one block per class). 64 samples per block-iteration (16
// groups x 4 samples); avg class count ~33 -> usually ONE iteration. Each
// lane holds 4 float4 accumulators; one ds_read_b128 of a w row feeds 4
// samples -> 4x less w-LDS traffic than 1-sample-per-group.
__global__ __launch_bounds__(256) void k_main(
    const float* __restrict__ xg, const int* __restrict__ offs,
    const float* __restrict__ w, const float* __restrict__ bias,
    float* __restrict__ otb) {
  __shared__ float wl[4096];        // w[c]: 16 KB
  __shared__ float xs[64][68];      // 64 samples' x, padded rows (17.4 KB)

  const int tid = threadIdx.x;
  const int c   = blockIdx.x;
  const int start = offs[c];
  const int count = offs[c + 1] - start;

  // stage w[c] into LDS (coalesced: wave reads 1KB contiguous per inst)
  const float* wp = w + (size_t)c * (M_DIM * N_OUTD);
#pragma unroll
  for (int p = 0; p < 4; ++p) {
    const int idx = (p * 256 + tid) * 4;
    *(float4v*)(&wl[idx]) = *(const float4v*)(wp + idx);
  }

  const int wid  = tid >> 6;
  const int lane = tid & 63;
  const int G    = wid * 4 + (lane >> 4);   // group 0..15
  const int oi   = (lane & 15) * 4;         // output base (float4)
  const int jb   = G * 4;                   // this group's first sample slot

  const float4v bv = *(const float4v*)(bias + (size_t)c * N_OUTD + oi);

  for (int s0 = 0; s0 < count; s0 += 64) {
    __syncthreads();  // xs reuse guard (iter>0); wl ready (iter 0)
    // stage up to 64 samples (contiguous 16KB block of xg)
#pragma unroll
    for (int p = 0; p < 4; ++p) {
      const int idx = p * 256 + tid;
      const int row = idx >> 4;             // 0..63
      const int c4  = (idx & 15) * 4;
      if (s0 + row < count)
        *(float4v*)(&xs[row][c4]) = *(const float4v*)(xg + (size_t)(start + s0 + row) * M_DIM + c4);
    }
    __syncthreads();

    if (s0 + jb < count) {
      float4v a0 = bv, a1 = bv, a2 = bv, a3 = bv;
#pragma unroll 8
      for (int m = 0; m < M_DIM; ++m) {
        const float4v wv = *(const float4v*)(&wl[m * N_OUTD + oi]);  // b128, shared by 4 samples
        a0 += xs[jb + 0][m] * wv;
        a1 += xs[jb + 1][m] * wv;   // rows beyond count read garbage; stores guarded
        a2 += xs[jb + 2][m] * wv;
        a3 += xs[jb + 3][m] * wv;
      }
      float* ob = otb + (size_t)(start + s0 + jb) * N_OUTD + oi;
      *(float4v*)(ob) = a0;                                      // jb+0 < count
      if (s0 + jb + 1 < count) *(float4v*)(ob + 1 * N_OUTD) = a1;
      if (s0 + jb + 2 < count) *(float4v*)(ob + 2 * N_OUTD) = a2;
      if (s0 + jb + 3 < count) *(float4v*)(ob + 3 * N_OUTD) = a3;
    }
  }
}

// ============ kernel 4: gather + transpose-out (512 blocks) =================
// out[b][o][l] = otb[rank[b*L+l]][o]; one 64o x 64l tile per block.
__global__ __launch_bounds__(256) void k_tout(
    const float* __restrict__ otb, const int* __restrict__ rank,
    float* __restrict__ out) {
  __shared__ float tile[64][68];  // [o][l], padded
  __shared__ int rk[64];
  const int tid = threadIdx.x;
  const int b  = blockIdx.x >> 7;
  const int l0 = (blockIdx.x & 127) << 6;

  if (tid < 64) rk[tid] = rank[b * L_DIM + l0 + tid];
  __syncthreads();

  const int r  = tid >> 4;
  const int c4 = (tid & 15) * 4;
#pragma unroll
  for (int p = 0; p < 4; ++p) {
    const int li = r + 16 * p;
    float4v v = *(const float4v*)(otb + (size_t)rk[li] * N_OUTD + c4);  // 256B/row
#pragma unroll
    for (int q = 0; q < 4; ++q) tile[c4 + q][li] = v[q];
  }
  __syncthreads();
  float* ob = out + ((size_t)b * N_OUTD) * L_DIM + l0;
#pragma unroll
  for (int p = 0; p < 4; ++p) {
    const int o = r + 16 * p;
    float4v v = *(const float4v*)(&tile[o][c4]);
    *(float4v*)(ob + (size_t)o * L_DIM + c4) = v;  // 64B-line writes
  }
}

// ============ fallback (R4 kernel) if ws too small ==========================
#define TL 16
__global__ __launch_bounds__(256) void condmul_fallback(
    const float* __restrict__ x, const int* __restrict__ inds,
    const float* __restrict__ w, const float* __restrict__ bias,
    float* __restrict__ out) {
  __shared__ float xs[M_DIM][TL];
  __shared__ float os[TL][N_OUTD + 4];
  const int tid  = threadIdx.x;
  const int wid  = tid >> 6;
  const int lane = tid & 63;
  const int g    = lane >> 4;
  const int oi   = (lane & 15) * 4;
  const int n0   = blockIdx.x * TL;
  const int b    = n0 / L_DIM;
  const int l0   = n0 % L_DIM;
  {
    const int li = tid & (TL - 1);
    const int m0 = tid >> 4;
    const float* xb = x + ((size_t)b * M_DIM) * L_DIM + l0;
#pragma unroll
    for (int p = 0; p < 4; ++p) {
      const int m = p * 16 + m0;
      xs[m][li] = xb[(size_t)m * L_DIM + li];
    }
  }
  __syncthreads();
  const int li = wid * 4 + g;
  const int c  = inds[n0 + li];
  const float* wp = w + ((size_t)c * M_DIM) * N_OUTD + oi;
  float4v acc = {0.f, 0.f, 0.f, 0.f};
#pragma unroll 8
  for (int m = 0; m < M_DIM; ++m) {
    const float  xv = xs[m][li];
    const float4v wv = *(const float4v*)(wp + (size_t)m * N_OUTD);
    acc += xv * wv;
  }
  acc += *(const float4v*)(bias + (size_t)c * N_OUTD + oi);
  *(float4v*)(&os[li][oi]) = acc;
  __syncthreads();
  {
    const int lo = tid & (TL - 1);
    const int o0 = tid >> 4;
    float* ob = out + ((size_t)b * N_OUTD) * L_DIM + l0;
#pragma unroll
    for (int p = 0; p < 4; ++p) {
      const int o = p * 16 + o0;
      ob[(size_t)o * L_DIM + lo] = os[lo][o];
    }
  }
}

extern "C" void kernel_launch(void* const* d_in, const int* in_sizes, int n_in,
                              void* d_out, int out_size, void* d_ws, size_t ws_size,
                              hipStream_t stream) {
  const float* x    = (const float*)d_in[0];
  const int*   inds = (const int*)d_in[1];
  const float* w    = (const float*)d_in[2];
  const float* bias = (const float*)d_in[3];
  float*       out  = (float*)d_out;

  if (ws_size < WS_NEED) {
    condmul_fallback<<<NSAMP / TL, 256, 0, stream>>>(x, inds, w, bias, out);
    return;
  }

  char* ws = (char*)d_ws;
  float* xg   = (float*)(ws + XG_OFF);
  float* otb  = (float*)(ws + OTB_OFF);
  int*   rank = (int*)(ws + RANK_OFF);
  int*   offs = (int*)(ws + OFFS_OFF);
  int*   cur  = (int*)(ws + CUR_OFF);

  k_binprep<<<1, 1024, 0, stream>>>(inds, offs, cur);
  k_tin_scatter<<<512, 256, 0, stream>>>(x, inds, cur, xg, rank);
  k_main<<<NCLS, 256, 0, stream>>>(xg, offs, w, bias, otb);
  k_tout<<<512, 256, 0, stream>>>(otb, rank, out);
}